// Round 2
// baseline (810.439 us; speedup 1.0000x reference)
//
#include <hip/hip_runtime.h>
#include <hip/hip_fp16.h>

// GCN 2-layer forward, MI355X. R13: dst-counting-sort + atomic-free accs.
// R12 post-mortem: top-5 shows acc1/acc2 (u64 LDS atomic passes) at 94-95us
// are the two slowest kernels; reorder/dinv (u32 atomics) are each <94us.
// => u32 LDS atomic ~1.8cyc/edge, u64 ~3.5cyc/edge. Removing a u32 pass
// (R12) was neutral; the u64 passes are the target.
// R13: k_sortwin fuses per-dst count + scan + place (2 u32 passes) to build
// a fully dst-sorted edge list perm2 + per-dst offsets offs[]; acc1/acc2
// become atomic-free gather-reduce in fp32 registers (thread owns 4 dsts).
// dinv/deg arrays dropped (dv recomputed from offs deltas).
// Pipeline: zero_fill, reorder(slab), sortwin(count+place), gacc1, gacc2.

constexpr int W_SHIFT = 11;
constexpr int W = 2048;            // nodes per dst window
constexpr int MAXB = 512;          // max buckets/windows
constexpr int RB = 1024;           // reorder block threads
constexpr int CHUNK = 8192;        // edges per reorder block
constexpr int CAP = 28;            // reorder slab capacity per bucket
constexpr int AB = 512;            // accumulate/sort block threads

constexpr float SCALE1 = 65536.0f;        // fixed-point consts (R12 fallback)
constexpr float INV1   = 1.0f / 65536.0f;
constexpr unsigned BIAS1 = 1u << 20;
constexpr float SCALE2 = 4096.0f;
constexpr float INV2   = 1.0f / 4096.0f;
constexpr unsigned BIAS2 = 1u << 22;

typedef unsigned uv4 __attribute__((ext_vector_type(4)));
typedef int      iv4 __attribute__((ext_vector_type(4)));

__device__ __forceinline__ unsigned long long pack2(float a, float b,
                                                    float scale, unsigned bias) {
    unsigned lo = (unsigned)(__float2int_rn(a * scale) + (int)bias);
    unsigned hi = (unsigned)(__float2int_rn(b * scale) + (int)bias);
    return (unsigned long long)lo | ((unsigned long long)hi << 32);
}

__global__ __launch_bounds__(256) void k_zero_fill(unsigned* __restrict__ fill,
                                                   int nb, unsigned C) {
    int i = blockIdx.x * 256 + threadIdx.x;
    if (i < nb) fill[i] = (unsigned)i * C;
}

// Slab multisplit: single u32 LDS atomic per edge (R12, measured-good).
__global__ __launch_bounds__(RB) void k_reorder(const int* __restrict__ src,
                                                const int* __restrict__ dst,
                                                unsigned* __restrict__ fill,
                                                unsigned* __restrict__ perm, int E) {
    __shared__ unsigned slab[MAXB * CAP];  // 57344 B
    __shared__ unsigned ptr[MAXB];
    __shared__ unsigned gbase[MAXB];
    int tid = threadIdx.x;
    if (tid < MAXB) ptr[tid] = 0u;
    __syncthreads();
    long base0 = (long)blockIdx.x * CHUNK;
    int total = (int)min((long)CHUNK, (long)E - base0);
    bool full = (total == CHUNK);

    if (full) {
        const iv4* dv4 = (const iv4*)(dst + base0);
        const iv4* sv4 = (const iv4*)(src + base0);
        #pragma unroll
        for (int k = 0; k < 2; k++) {
            iv4 dq = dv4[k * RB + tid];
            iv4 sq = sv4[k * RB + tid];
            unsigned d, b, val, lpos;
            d = (unsigned)dq.x; b = d >> W_SHIFT;
            val = (unsigned)sq.x | ((d & (W - 1)) << 20);
            lpos = atomicAdd(&ptr[b], 1u);
            if (lpos < (unsigned)CAP) slab[b * CAP + lpos] = val;
            else perm[atomicAdd(&fill[b], 1u)] = val;
            d = (unsigned)dq.y; b = d >> W_SHIFT;
            val = (unsigned)sq.y | ((d & (W - 1)) << 20);
            lpos = atomicAdd(&ptr[b], 1u);
            if (lpos < (unsigned)CAP) slab[b * CAP + lpos] = val;
            else perm[atomicAdd(&fill[b], 1u)] = val;
            d = (unsigned)dq.z; b = d >> W_SHIFT;
            val = (unsigned)sq.z | ((d & (W - 1)) << 20);
            lpos = atomicAdd(&ptr[b], 1u);
            if (lpos < (unsigned)CAP) slab[b * CAP + lpos] = val;
            else perm[atomicAdd(&fill[b], 1u)] = val;
            d = (unsigned)dq.w; b = d >> W_SHIFT;
            val = (unsigned)sq.w | ((d & (W - 1)) << 20);
            lpos = atomicAdd(&ptr[b], 1u);
            if (lpos < (unsigned)CAP) slab[b * CAP + lpos] = val;
            else perm[atomicAdd(&fill[b], 1u)] = val;
        }
    } else {
        for (int li = tid; li < total; li += RB) {
            unsigned d = (unsigned)dst[base0 + li];
            unsigned s = (unsigned)src[base0 + li];
            unsigned b = d >> W_SHIFT;
            unsigned val = s | ((d & (W - 1)) << 20);
            unsigned lpos = atomicAdd(&ptr[b], 1u);
            if (lpos < (unsigned)CAP) slab[b * CAP + lpos] = val;
            else perm[atomicAdd(&fill[b], 1u)] = val;
        }
    }
    __syncthreads();
    if (tid < MAXB) {
        unsigned cnt = min(ptr[tid], (unsigned)CAP);
        gbase[tid] = cnt ? atomicAdd(&fill[tid], cnt) : 0u;
        ptr[tid] = cnt;
    }
    __syncthreads();
    for (int s = tid; s < MAXB * CAP; s += RB) {
        int b = s / CAP;
        int i = s - b * CAP;
        if (i < (int)ptr[b]) perm[gbase[b] + i] = slab[s];
    }
}

// Per-window: count per-dst (x2-replicated u32 atomics) -> scan -> offs/dinv/xs
// -> place into globally dst-sorted perm2 (u32 atomics on single-copy ptrs).
__global__ __launch_bounds__(AB) void k_sortwin(const unsigned* __restrict__ perm,
                                                const unsigned* __restrict__ fill,
                                                const float2* __restrict__ x,
                                                __half2* __restrict__ xs,
                                                unsigned* __restrict__ offs,
                                                unsigned* __restrict__ perm2,
                                                int N, unsigned C, int NB) {
    __shared__ unsigned cnt[2 * W];   // counts (x2-interleaved) -> abs ptrs [0..W)
    __shared__ unsigned scn[AB];
    __shared__ unsigned sh_base, sh_tot;
    const int tid = threadIdx.x;
    const int b = blockIdx.x;

    // window-base scan (each block computes its own global base)
    unsigned wsz = (tid < NB) ? (fill[tid] - (unsigned)tid * C) : 0u;
    scn[tid] = wsz;
    __syncthreads();
    for (int off = 1; off < AB; off <<= 1) {
        unsigned u = (tid >= off) ? scn[tid - off] : 0u;
        __syncthreads();
        scn[tid] += u;
        __syncthreads();
    }
    if (tid == 0) {
        sh_base = (b > 0) ? scn[b - 1] : 0u;
        sh_tot  = scn[AB - 1];
    }
    for (int i = tid; i < 2 * W; i += AB) cnt[i] = 0u;
    __syncthreads();

    // ---- count pass ----
    unsigned s = (unsigned)b * C, e = fill[b];
    unsigned m = e - s, nv8 = m >> 3;
    unsigned par = tid & 1u;
    const uv4* p4 = (const uv4*)(perm + s);
    for (unsigned j = tid; j < nv8; j += AB) {
        uv4 qa = __builtin_nontemporal_load(p4 + 2u * j);
        uv4 qb = __builtin_nontemporal_load(p4 + 2u * j + 1u);
        atomicAdd(&cnt[((qa.x >> 20) << 1) | par], 1u);
        atomicAdd(&cnt[((qa.y >> 20) << 1) | par], 1u);
        atomicAdd(&cnt[((qa.z >> 20) << 1) | par], 1u);
        atomicAdd(&cnt[((qa.w >> 20) << 1) | par], 1u);
        atomicAdd(&cnt[((qb.x >> 20) << 1) | par], 1u);
        atomicAdd(&cnt[((qb.y >> 20) << 1) | par], 1u);
        atomicAdd(&cnt[((qb.z >> 20) << 1) | par], 1u);
        atomicAdd(&cnt[((qb.w >> 20) << 1) | par], 1u);
    }
    unsigned t8 = s + (nv8 << 3) + (unsigned)tid;
    if (t8 < e) atomicAdd(&cnt[((perm[t8] >> 20) << 1) | par], 1u);
    __syncthreads();

    // ---- merge + block scan of 2048 counts -> absolute offsets ----
    int l0 = 4 * tid;
    unsigned c0 = cnt[2 * l0]     + cnt[2 * l0 + 1];
    unsigned c1 = cnt[2 * l0 + 2] + cnt[2 * l0 + 3];
    unsigned c2 = cnt[2 * l0 + 4] + cnt[2 * l0 + 5];
    unsigned c3 = cnt[2 * l0 + 6] + cnt[2 * l0 + 7];
    unsigned sum4 = c0 + c1 + c2 + c3;
    scn[tid] = sum4;
    __syncthreads();
    for (int off = 1; off < AB; off <<= 1) {
        unsigned u = (tid >= off) ? scn[tid - off] : 0u;
        __syncthreads();
        scn[tid] += u;
        __syncthreads();
    }
    unsigned base = sh_base + (scn[tid] - sum4);
    unsigned o0 = base, o1 = o0 + c0, o2 = o1 + c1, o3 = o2 + c2;
    // all count reads happened before scan2's barriers -> safe to overwrite cnt
    cnt[l0] = o0; cnt[l0 + 1] = o1; cnt[l0 + 2] = o2; cnt[l0 + 3] = o3;

    int d0 = (b << W_SHIFT) + l0;
    if (d0     <= N) offs[d0]     = o0;
    if (d0 + 1 <= N) offs[d0 + 1] = o1;
    if (d0 + 2 <= N) offs[d0 + 2] = o2;
    if (d0 + 3 <= N) offs[d0 + 3] = o3;
    if (b == 0 && tid == 0) offs[N] = sh_tot;   // sentinel (same value if dup)

    unsigned cc[4] = {c0, c1, c2, c3};
    #pragma unroll
    for (int k = 0; k < 4; k++) {
        int d = d0 + k;
        if (d < N) {
            float dv = 1.0f / sqrtf((float)cc[k] + 1.0f);   // +1 self-loop
            float2 xv = x[d];
            xs[d] = __floats2half2_rn(xv.x * dv, xv.y * dv);
        }
    }
    __syncthreads();

    // ---- place pass ----
    for (unsigned j = tid; j < nv8; j += AB) {
        uv4 qa = __builtin_nontemporal_load(p4 + 2u * j);
        uv4 qb = __builtin_nontemporal_load(p4 + 2u * j + 1u);
        unsigned p;
        p = atomicAdd(&cnt[qa.x >> 20], 1u); perm2[p] = qa.x & 0xFFFFFu;
        p = atomicAdd(&cnt[qa.y >> 20], 1u); perm2[p] = qa.y & 0xFFFFFu;
        p = atomicAdd(&cnt[qa.z >> 20], 1u); perm2[p] = qa.z & 0xFFFFFu;
        p = atomicAdd(&cnt[qa.w >> 20], 1u); perm2[p] = qa.w & 0xFFFFFu;
        p = atomicAdd(&cnt[qb.x >> 20], 1u); perm2[p] = qb.x & 0xFFFFFu;
        p = atomicAdd(&cnt[qb.y >> 20], 1u); perm2[p] = qb.y & 0xFFFFFu;
        p = atomicAdd(&cnt[qb.z >> 20], 1u); perm2[p] = qb.z & 0xFFFFFu;
        p = atomicAdd(&cnt[qb.w >> 20], 1u); perm2[p] = qb.w & 0xFFFFFu;
    }
    if (t8 < e) {
        unsigned v = perm[t8];
        unsigned p = atomicAdd(&cnt[v >> 20], 1u);
        perm2[p] = v & 0xFFFFFu;
    }
}

// layer1: atomic-free gather-reduce (thread owns 4 consecutive dsts) + MLP
__global__ __launch_bounds__(AB) void k_gacc1(const unsigned* __restrict__ perm2,
                                              const unsigned* __restrict__ offs,
                                              const __half2* __restrict__ xs,
                                              const float* __restrict__ W1,
                                              const float* __restrict__ b1,
                                              const float* __restrict__ W2,
                                              __half2* __restrict__ h2s, int N) {
    int d0 = (blockIdx.x << W_SHIFT) + 4 * (int)threadIdx.x;
    if (d0 >= N) return;
    uv4 ov = *(const uv4*)(offs + d0);
    unsigned o4 = offs[d0 + 4];
    float w10 = W1[0], w11 = W1[1], w12 = W1[2], w13 = W1[3];
    float w14 = W1[4], w15 = W1[5], w16 = W1[6], w17 = W1[7];
    float bb0 = b1[0], bb1 = b1[1], bb2 = b1[2], bb3 = b1[3];
    float u0 = W2[0], u1 = W2[1], u2 = W2[2], u3 = W2[3];
    float u4 = W2[4], u5 = W2[5], u6 = W2[6], u7 = W2[7];
    unsigned stA[4] = {ov.x, ov.y, ov.z, ov.w};
    unsigned enA[4] = {ov.y, ov.z, ov.w, o4};
    #pragma unroll
    for (int k = 0; k < 4; k++) {
        int d = d0 + k;
        if (d < N) {
            unsigned st = stA[k], en = enA[k];
            float dv = 1.0f / sqrtf((float)(en - st) + 1.0f);
            float2 self = __half22float2(xs[d]);
            float Sx = self.x, Sy = self.y;
            unsigned i = st;
            for (; i + 4 <= en; i += 4) {
                unsigned s0 = perm2[i], s1 = perm2[i + 1];
                unsigned s2 = perm2[i + 2], s3 = perm2[i + 3];
                float2 v0 = __half22float2(xs[s0]);
                float2 v1 = __half22float2(xs[s1]);
                float2 v2 = __half22float2(xs[s2]);
                float2 v3 = __half22float2(xs[s3]);
                Sx += (v0.x + v1.x) + (v2.x + v3.x);
                Sy += (v0.y + v1.y) + (v2.y + v3.y);
            }
            for (; i < en; i++) {
                float2 v = __half22float2(xs[perm2[i]]);
                Sx += v.x; Sy += v.y;
            }
            float a0 = fmaxf(fmaf(Sy, w14, Sx * w10) * dv + bb0, 0.0f);
            float a1 = fmaxf(fmaf(Sy, w15, Sx * w11) * dv + bb1, 0.0f);
            float a2 = fmaxf(fmaf(Sy, w16, Sx * w12) * dv + bb2, 0.0f);
            float a3 = fmaxf(fmaf(Sy, w17, Sx * w13) * dv + bb3, 0.0f);
            float hx = (a0 * u0 + a1 * u2 + a2 * u4 + a3 * u6) * dv;
            float hy = (a0 * u1 + a1 * u3 + a2 * u5 + a3 * u7) * dv;
            h2s[d] = __floats2half2_rn(hx, hy);
        }
    }
}

// layer2: atomic-free gather-reduce + bias, fp32 accumulation
__global__ __launch_bounds__(AB) void k_gacc2(const unsigned* __restrict__ perm2,
                                              const unsigned* __restrict__ offs,
                                              const __half2* __restrict__ h2s,
                                              const float* __restrict__ b2,
                                              float2* __restrict__ out, int N) {
    int d0 = (blockIdx.x << W_SHIFT) + 4 * (int)threadIdx.x;
    if (d0 >= N) return;
    uv4 ov = *(const uv4*)(offs + d0);
    unsigned o4 = offs[d0 + 4];
    float bb0 = b2[0], bb1 = b2[1];
    unsigned stA[4] = {ov.x, ov.y, ov.z, ov.w};
    unsigned enA[4] = {ov.y, ov.z, ov.w, o4};
    #pragma unroll
    for (int k = 0; k < 4; k++) {
        int d = d0 + k;
        if (d < N) {
            unsigned st = stA[k], en = enA[k];
            float dv = 1.0f / sqrtf((float)(en - st) + 1.0f);
            float2 self = __half22float2(h2s[d]);
            float Sx = self.x, Sy = self.y;
            unsigned i = st;
            for (; i + 4 <= en; i += 4) {
                unsigned s0 = perm2[i], s1 = perm2[i + 1];
                unsigned s2 = perm2[i + 2], s3 = perm2[i + 3];
                float2 v0 = __half22float2(h2s[s0]);
                float2 v1 = __half22float2(h2s[s1]);
                float2 v2 = __half22float2(h2s[s2]);
                float2 v3 = __half22float2(h2s[s3]);
                Sx += (v0.x + v1.x) + (v2.x + v3.x);
                Sy += (v0.y + v1.y) + (v2.y + v3.y);
            }
            for (; i < en; i++) {
                float2 v = __half22float2(h2s[perm2[i]]);
                Sx += v.x; Sy += v.y;
            }
            out[d] = make_float2(Sx * dv + bb0, Sy * dv + bb1);
        }
    }
}

// ---------- R12 fast path (fallback if perm2 doesn't fit) ----------

__global__ __launch_bounds__(AB) void k_dinv(const unsigned* __restrict__ perm,
                                             const unsigned* __restrict__ fill,
                                             const float2* __restrict__ x,
                                             float* __restrict__ dinv,
                                             unsigned* __restrict__ deg,
                                             __half2* __restrict__ xs,
                                             int N, unsigned C) {
    __shared__ unsigned c[2 * W];
    for (int i = threadIdx.x; i < 2 * W; i += AB) c[i] = 0u;
    __syncthreads();
    int b = blockIdx.x;
    unsigned par = threadIdx.x & 1u;
    unsigned s = (unsigned)b * C, e = fill[b];
    unsigned m = e - s, nv8 = m >> 3;
    const uv4* p4 = (const uv4*)(perm + s);
    for (unsigned j = threadIdx.x; j < nv8; j += AB) {
        uv4 qa = __builtin_nontemporal_load(p4 + 2u * j);
        uv4 qb = __builtin_nontemporal_load(p4 + 2u * j + 1u);
        atomicAdd(&c[((qa.x >> 20) << 1) | par], 1u);
        atomicAdd(&c[((qa.y >> 20) << 1) | par], 1u);
        atomicAdd(&c[((qa.z >> 20) << 1) | par], 1u);
        atomicAdd(&c[((qa.w >> 20) << 1) | par], 1u);
        atomicAdd(&c[((qb.x >> 20) << 1) | par], 1u);
        atomicAdd(&c[((qb.y >> 20) << 1) | par], 1u);
        atomicAdd(&c[((qb.z >> 20) << 1) | par], 1u);
        atomicAdd(&c[((qb.w >> 20) << 1) | par], 1u);
    }
    unsigned t = s + (nv8 << 3) + threadIdx.x;
    if (t < e) atomicAdd(&c[((perm[t] >> 20) << 1) | par], 1u);
    __syncthreads();
    int d0 = b << W_SHIFT;
    for (int l = threadIdx.x; l < W; l += AB) {
        int d = d0 + l;
        if (d < N) {
            unsigned cn = c[2 * l] + c[2 * l + 1];
            float dv = 1.0f / sqrtf((float)(cn + 1u));
            dinv[d] = dv;
            deg[d] = cn;
            float2 xv = x[d];
            xs[d] = __floats2half2_rn(xv.x * dv, xv.y * dv);
        }
    }
}

__global__ __launch_bounds__(AB) void k_acc1(const unsigned* __restrict__ perm,
                                             const unsigned* __restrict__ fill,
                                             const __half2* __restrict__ xs,
                                             const float* __restrict__ dinv,
                                             const unsigned* __restrict__ deg,
                                             const float* __restrict__ W1,
                                             const float* __restrict__ b1,
                                             const float* __restrict__ W2,
                                             __half2* __restrict__ h2s,
                                             int N, unsigned C) {
    __shared__ unsigned long long acc[2 * W];
    for (int i = threadIdx.x; i < 2 * W; i += AB) acc[i] = 0ull;
    __syncthreads();
    int b = blockIdx.x;
    unsigned par = threadIdx.x & 1u;
    unsigned s = (unsigned)b * C, e = fill[b];
    unsigned m = e - s, nv8 = m >> 3;
    const uv4* p4 = (const uv4*)(perm + s);
    for (unsigned j = threadIdx.x; j < nv8; j += AB) {
        uv4 qa = __builtin_nontemporal_load(p4 + 2u * j);
        uv4 qb = __builtin_nontemporal_load(p4 + 2u * j + 1u);
        float2 v0 = __half22float2(xs[qa.x & 0xFFFFFu]);
        float2 v1 = __half22float2(xs[qa.y & 0xFFFFFu]);
        float2 v2 = __half22float2(xs[qa.z & 0xFFFFFu]);
        float2 v3 = __half22float2(xs[qa.w & 0xFFFFFu]);
        float2 v4 = __half22float2(xs[qb.x & 0xFFFFFu]);
        float2 v5 = __half22float2(xs[qb.y & 0xFFFFFu]);
        float2 v6 = __half22float2(xs[qb.z & 0xFFFFFu]);
        float2 v7 = __half22float2(xs[qb.w & 0xFFFFFu]);
        atomicAdd(&acc[((qa.x >> 20) << 1) | par], pack2(v0.x, v0.y, SCALE1, BIAS1));
        atomicAdd(&acc[((qa.y >> 20) << 1) | par], pack2(v1.x, v1.y, SCALE1, BIAS1));
        atomicAdd(&acc[((qa.z >> 20) << 1) | par], pack2(v2.x, v2.y, SCALE1, BIAS1));
        atomicAdd(&acc[((qa.w >> 20) << 1) | par], pack2(v3.x, v3.y, SCALE1, BIAS1));
        atomicAdd(&acc[((qb.x >> 20) << 1) | par], pack2(v4.x, v4.y, SCALE1, BIAS1));
        atomicAdd(&acc[((qb.y >> 20) << 1) | par], pack2(v5.x, v5.y, SCALE1, BIAS1));
        atomicAdd(&acc[((qb.z >> 20) << 1) | par], pack2(v6.x, v6.y, SCALE1, BIAS1));
        atomicAdd(&acc[((qb.w >> 20) << 1) | par], pack2(v7.x, v7.y, SCALE1, BIAS1));
    }
    unsigned t = s + (nv8 << 3) + threadIdx.x;
    if (t < e) {
        unsigned p = perm[t];
        float2 v = __half22float2(xs[p & 0xFFFFFu]);
        atomicAdd(&acc[((p >> 20) << 1) | par], pack2(v.x, v.y, SCALE1, BIAS1));
    }
    __syncthreads();
    int d0 = b << W_SHIFT;
    float w10 = W1[0], w11 = W1[1], w12 = W1[2], w13 = W1[3];
    float w14 = W1[4], w15 = W1[5], w16 = W1[6], w17 = W1[7];
    float bb0 = b1[0], bb1 = b1[1], bb2 = b1[2], bb3 = b1[3];
    float u0 = W2[0], u1 = W2[1], u2 = W2[2], u3 = W2[3];
    float u4 = W2[4], u5 = W2[5], u6 = W2[6], u7 = W2[7];
    for (int l = threadIdx.x; l < W; l += AB) {
        int d = d0 + l;
        if (d < N) {
            float dv = dinv[d];
            unsigned cn = deg[d];
            unsigned long long a64 = acc[2 * l] + acc[2 * l + 1];
            unsigned lo = (unsigned)a64, hi = (unsigned)(a64 >> 32);
            float2 self = __half22float2(xs[d]);
            float Sx = (float)(int)(lo - cn * BIAS1) * INV1 + self.x;
            float Sy = (float)(int)(hi - cn * BIAS1) * INV1 + self.y;
            float a0 = fmaxf(fmaf(Sy, w14, Sx * w10) * dv + bb0, 0.0f);
            float a1 = fmaxf(fmaf(Sy, w15, Sx * w11) * dv + bb1, 0.0f);
            float a2 = fmaxf(fmaf(Sy, w16, Sx * w12) * dv + bb2, 0.0f);
            float a3 = fmaxf(fmaf(Sy, w17, Sx * w13) * dv + bb3, 0.0f);
            float hx = (a0 * u0 + a1 * u2 + a2 * u4 + a3 * u6) * dv;
            float hy = (a0 * u1 + a1 * u3 + a2 * u5 + a3 * u7) * dv;
            h2s[d] = __floats2half2_rn(hx, hy);
        }
    }
}

__global__ __launch_bounds__(AB) void k_acc2(const unsigned* __restrict__ perm,
                                             const unsigned* __restrict__ fill,
                                             const __half2* __restrict__ h2s,
                                             const float* __restrict__ dinv,
                                             const unsigned* __restrict__ deg,
                                             const float* __restrict__ b2,
                                             float2* __restrict__ out,
                                             int N, unsigned C) {
    __shared__ unsigned long long acc[2 * W];
    for (int i = threadIdx.x; i < 2 * W; i += AB) acc[i] = 0ull;
    __syncthreads();
    int b = blockIdx.x;
    unsigned par = threadIdx.x & 1u;
    unsigned s = (unsigned)b * C, e = fill[b];
    unsigned m = e - s, nv8 = m >> 3;
    const uv4* p4 = (const uv4*)(perm + s);
    for (unsigned j = threadIdx.x; j < nv8; j += AB) {
        uv4 qa = __builtin_nontemporal_load(p4 + 2u * j);
        uv4 qb = __builtin_nontemporal_load(p4 + 2u * j + 1u);
        float2 v0 = __half22float2(h2s[qa.x & 0xFFFFFu]);
        float2 v1 = __half22float2(h2s[qa.y & 0xFFFFFu]);
        float2 v2 = __half22float2(h2s[qa.z & 0xFFFFFu]);
        float2 v3 = __half22float2(h2s[qa.w & 0xFFFFFu]);
        float2 v4 = __half22float2(h2s[qb.x & 0xFFFFFu]);
        float2 v5 = __half22float2(h2s[qb.y & 0xFFFFFu]);
        float2 v6 = __half22float2(h2s[qb.z & 0xFFFFFu]);
        float2 v7 = __half22float2(h2s[qb.w & 0xFFFFFu]);
        atomicAdd(&acc[((qa.x >> 20) << 1) | par], pack2(v0.x, v0.y, SCALE2, BIAS2));
        atomicAdd(&acc[((qa.y >> 20) << 1) | par], pack2(v1.x, v1.y, SCALE2, BIAS2));
        atomicAdd(&acc[((qa.z >> 20) << 1) | par], pack2(v2.x, v2.y, SCALE2, BIAS2));
        atomicAdd(&acc[((qa.w >> 20) << 1) | par], pack2(v3.x, v3.y, SCALE2, BIAS2));
        atomicAdd(&acc[((qb.x >> 20) << 1) | par], pack2(v4.x, v4.y, SCALE2, BIAS2));
        atomicAdd(&acc[((qb.y >> 20) << 1) | par], pack2(v5.x, v5.y, SCALE2, BIAS2));
        atomicAdd(&acc[((qb.z >> 20) << 1) | par], pack2(v6.x, v6.y, SCALE2, BIAS2));
        atomicAdd(&acc[((qb.w >> 20) << 1) | par], pack2(v7.x, v7.y, SCALE2, BIAS2));
    }
    unsigned t = s + (nv8 << 3) + threadIdx.x;
    if (t < e) {
        unsigned p = perm[t];
        float2 v = __half22float2(h2s[p & 0xFFFFFu]);
        atomicAdd(&acc[((p >> 20) << 1) | par], pack2(v.x, v.y, SCALE2, BIAS2));
    }
    __syncthreads();
    int d0 = b << W_SHIFT;
    float bb0 = b2[0], bb1 = b2[1];
    for (int l = threadIdx.x; l < W; l += AB) {
        int d = d0 + l;
        if (d < N) {
            float dv = dinv[d];
            unsigned cn = deg[d];
            unsigned long long a64 = acc[2 * l] + acc[2 * l + 1];
            unsigned lo = (unsigned)a64, hi = (unsigned)(a64 >> 32);
            float2 v = __half22float2(h2s[d]);
            float Sx = (float)(int)(lo - cn * BIAS2) * INV2 + v.x;
            float Sy = (float)(int)(hi - cn * BIAS2) * INV2 + v.y;
            out[d] = make_float2(Sx * dv + bb0, Sy * dv + bb1);
        }
    }
}

// ---------------- fallback (R1-style, only if workspace too small) ----------

__global__ __launch_bounds__(256) void f_init_deg(unsigned* deg, int n) {
    int i = blockIdx.x * 256 + threadIdx.x;
    if (i < n) deg[i] = 1u;
}
__global__ __launch_bounds__(256) void f_count_deg(const int* dst, unsigned* deg, int E) {
    int e = blockIdx.x * 256 + threadIdx.x;
    if (e < E) atomicAdd(&deg[dst[e]], 1u);
}
__global__ __launch_bounds__(256) void f_node1(const float2* x, const float* W1,
                                               const unsigned* deg, float* dinv,
                                               float4* h1s, float4* agg1, int n) {
    int i = blockIdx.x * 256 + threadIdx.x;
    if (i >= n) return;
    float dv = 1.0f / sqrtf((float)deg[i]);
    dinv[i] = dv;
    float2 xv = x[i];
    float4 h;
    h.x = fmaf(xv.y, W1[4], xv.x * W1[0]) * dv;
    h.y = fmaf(xv.y, W1[5], xv.x * W1[1]) * dv;
    h.z = fmaf(xv.y, W1[6], xv.x * W1[2]) * dv;
    h.w = fmaf(xv.y, W1[7], xv.x * W1[3]) * dv;
    h1s[i] = h;
    agg1[i] = make_float4(h.x * dv, h.y * dv, h.z * dv, h.w * dv);
}
__global__ __launch_bounds__(256) void f_edge1(const int* src, const int* dst,
                                               const float* dinv, const float4* h1s,
                                               float* agg1, int E) {
    int e = blockIdx.x * 256 + threadIdx.x;
    if (e >= E) return;
    int s = src[e], d = dst[e];
    float w = dinv[d];
    float4 m = h1s[s];
    float* p = agg1 + 4ll * d;
    unsafeAtomicAdd(p + 0, m.x * w);
    unsafeAtomicAdd(p + 1, m.y * w);
    unsafeAtomicAdd(p + 2, m.z * w);
    unsafeAtomicAdd(p + 3, m.w * w);
}
__global__ __launch_bounds__(256) void f_node2(const float4* agg1, const float* b1,
                                               const float* W2, const float* b2,
                                               const float* dinv, float2* h2s,
                                               float2* out, int n) {
    int i = blockIdx.x * 256 + threadIdx.x;
    if (i >= n) return;
    float4 a = agg1[i];
    a.x = fmaxf(a.x + b1[0], 0.0f);
    a.y = fmaxf(a.y + b1[1], 0.0f);
    a.z = fmaxf(a.z + b1[2], 0.0f);
    a.w = fmaxf(a.w + b1[3], 0.0f);
    float dv = dinv[i];
    float2 h;
    h.x = (a.x * W2[0] + a.y * W2[2] + a.z * W2[4] + a.w * W2[6]) * dv;
    h.y = (a.x * W2[1] + a.y * W2[3] + a.z * W2[5] + a.w * W2[7]) * dv;
    h2s[i] = h;
    out[i] = make_float2(b2[0] + h.x * dv, b2[1] + h.y * dv);
}
__global__ __launch_bounds__(256) void f_edge2(const int* src, const int* dst,
                                               const float* dinv, const float2* h2s,
                                               float* out, int E) {
    int e = blockIdx.x * 256 + threadIdx.x;
    if (e >= E) return;
    int s = src[e], d = dst[e];
    float w = dinv[d];
    float2 m = h2s[s];
    float* p = out + 2ll * d;
    unsafeAtomicAdd(p + 0, m.x * w);
    unsafeAtomicAdd(p + 1, m.y * w);
}

extern "C" void kernel_launch(void* const* d_in, const int* in_sizes, int n_in,
                              void* d_out, int out_size, void* d_ws, size_t ws_size,
                              hipStream_t stream) {
    const float* x  = (const float*)d_in[0];
    const int* ei   = (const int*)d_in[1];
    const float* W1 = (const float*)d_in[2];
    const float* b1 = (const float*)d_in[3];
    const float* W2 = (const float*)d_in[4];
    const float* b2 = (const float*)d_in[5];
    float* out = (float*)d_out;

    const int N = in_sizes[0] / 2;
    const int E = in_sizes[1] / 2;
    const int* src = ei;
    const int* dst = ei + E;
    const int NB = (N + W - 1) >> W_SHIFT;

    char* ws = (char*)d_ws;
    const int gN = (N + 255) / 256;
    const int gE = (E + 255) / 256;

    const long Cmin = (long)(E / (NB > 0 ? NB : 1)) + 4096;
    auto rnd = [](size_t v) { return (v + 63) & ~(size_t)63; };

    // ---- tier 1: dst-sorted gather path ----
    size_t sz_xs   = rnd((size_t)4 * N);
    size_t sz_offs = rnd((size_t)4 * (N + 16));
    size_t sz_p2   = rnd((size_t)4 * (size_t)E);
    size_t fixed2  = 32768 + sz_xs + sz_xs + sz_offs + sz_p2 + 64;
    long avail2 = (long)ws_size - (long)fixed2;
    long Cmax2 = (avail2 > 0) ? avail2 / (4L * NB) : 0;
    long Cw2 = (Cmax2 > Cmin + 8192) ? (Cmin + 8192) : Cmax2;
    unsigned C2 = (unsigned)(Cw2 & ~7L);
    bool fast2 = ((long)C2 >= Cmin) && (NB <= MAXB) && (N <= (1 << 20)) && (E > 0);

    // ---- tier 2: R12 LDS-atomic path ----
    size_t fixed = 32768 + (size_t)16 * N;
    long avail = (long)ws_size - (long)fixed;
    long Cmax = (avail > 0) ? avail / (4L * NB) : 0;
    long Cw = (Cmax > Cmin + 8192) ? (Cmin + 8192) : Cmax;
    unsigned C = (unsigned)(Cw & ~7L);
    bool fast = ((long)C >= Cmin) && (NB <= MAXB) && (N <= (1 << 20));

    if (fast2) {
        unsigned* fill  = (unsigned*)ws;
        __half2*  xs    = (__half2*)(ws + 32768);
        __half2*  h2s   = (__half2*)(ws + 32768 + sz_xs);
        unsigned* offs  = (unsigned*)(ws + 32768 + 2 * sz_xs);
        unsigned* perm2 = (unsigned*)(ws + 32768 + 2 * sz_xs + sz_offs);
        unsigned* perm  = (unsigned*)(ws + 32768 + 2 * sz_xs + sz_offs + sz_p2);

        k_zero_fill<<<(NB + 255) / 256, 256, 0, stream>>>(fill, NB, C2);
        k_reorder<<<(E + CHUNK - 1) / CHUNK, RB, 0, stream>>>(src, dst, fill, perm, E);
        k_sortwin<<<NB, AB, 0, stream>>>(perm, fill, (const float2*)x, xs, offs,
                                         perm2, N, C2, NB);
        k_gacc1<<<NB, AB, 0, stream>>>(perm2, offs, xs, W1, b1, W2, h2s, N);
        k_gacc2<<<NB, AB, 0, stream>>>(perm2, offs, h2s, b2, (float2*)out, N);
    } else if (fast) {
        unsigned* fill = (unsigned*)(ws);
        float*    dinv = (float*)(ws + 32768);
        unsigned* deg  = (unsigned*)(ws + 32768 + (size_t)4 * N);
        __half2*  xs   = (__half2*)(ws + 32768 + (size_t)8 * N);
        __half2*  h2s  = (__half2*)(ws + 32768 + (size_t)12 * N);
        unsigned* perm = (unsigned*)(ws + fixed);

        k_zero_fill<<<(NB + 255) / 256, 256, 0, stream>>>(fill, NB, C);
        k_reorder<<<(E + CHUNK - 1) / CHUNK, RB, 0, stream>>>(src, dst, fill, perm, E);
        k_dinv<<<NB, AB, 0, stream>>>(perm, fill, (const float2*)x, dinv, deg, xs, N, C);
        k_acc1<<<NB, AB, 0, stream>>>(perm, fill, xs, dinv, deg, W1, b1, W2, h2s, N, C);
        k_acc2<<<NB, AB, 0, stream>>>(perm, fill, h2s, dinv, deg, b2, (float2*)out, N, C);
    } else {
        unsigned* deg = (unsigned*)(ws);
        float* dinv   = (float*)(ws + (size_t)4 * N);
        float* h1s    = (float*)(ws + (size_t)8 * N);
        float* agg1   = (float*)(ws + (size_t)24 * N);
        float* h2s    = h1s;

        f_init_deg<<<gN, 256, 0, stream>>>(deg, N);
        f_count_deg<<<gE, 256, 0, stream>>>(dst, deg, E);
        f_node1<<<gN, 256, 0, stream>>>((const float2*)x, W1, deg, dinv,
                                        (float4*)h1s, (float4*)agg1, N);
        f_edge1<<<gE, 256, 0, stream>>>(src, dst, dinv, (const float4*)h1s, agg1, E);
        f_node2<<<gN, 256, 0, stream>>>((const float4*)agg1, b1, W2, b2, dinv,
                                        (float2*)h2s, (float2*)out, N);
        f_edge2<<<gE, 256, 0, stream>>>(src, dst, dinv, (const float2*)h2s, out, E);
    }
}

// Round 3
// 493.579 us; speedup vs baseline: 1.6420x; 1.6420x over previous
//
#include <hip/hip_runtime.h>
#include <hip/hip_fp16.h>

// GCN 2-layer forward, MI355X. R14: dst-sort with LDS-staged coalesced
// writes + LDS-staged coalesced gathers.
// R13 post-mortem: (1) place phase scattered 4B global writes -> 483MB
// write-amp, 220us BW-bound; (2) gacc per-thread-segment reads -> 64-line
// wave scatters, ~200us each. Fixes: place stages quarters (512 dsts) in
// LDS and writes out coalesced; gacc stages quarter VALUES in LDS
// (coalesced perm2 read + random gather + swizzled LDS write), then
// per-dst serial sum from LDS.
// Atomic budget/edge: reorder 1 u32 + sortwin 2 u32 (vs R12's 2 u32 + 2 u64).
// Tiers: v5 sorted path -> R12 LDS-atomic path -> R1 fallback.

constexpr int W_SHIFT = 11;
constexpr int W = 2048;            // nodes per dst window
constexpr int MAXB = 512;          // max buckets/windows
constexpr int RB = 1024;           // reorder block threads
constexpr int CHUNK = 8192;        // edges per reorder block
constexpr int CAP = 28;            // reorder slab capacity per bucket
constexpr int AB = 512;            // sort/gacc block threads
constexpr int STG = 11264;         // quarter staging entries (44KB)

constexpr float SCALE1 = 65536.0f;        // fixed-point consts (R12 tier)
constexpr float INV1   = 1.0f / 65536.0f;
constexpr unsigned BIAS1 = 1u << 20;
constexpr float SCALE2 = 4096.0f;
constexpr float INV2   = 1.0f / 4096.0f;
constexpr unsigned BIAS2 = 1u << 22;

typedef unsigned uv4 __attribute__((ext_vector_type(4)));
typedef int      iv4 __attribute__((ext_vector_type(4)));

__device__ __forceinline__ unsigned long long pack2(float a, float b,
                                                    float scale, unsigned bias) {
    unsigned lo = (unsigned)(__float2int_rn(a * scale) + (int)bias);
    unsigned hi = (unsigned)(__float2int_rn(b * scale) + (int)bias);
    return (unsigned long long)lo | ((unsigned long long)hi << 32);
}

__global__ __launch_bounds__(256) void k_zero_fill(unsigned* __restrict__ fill,
                                                   int nb, unsigned C) {
    int i = blockIdx.x * 256 + threadIdx.x;
    if (i < nb) fill[i] = (unsigned)i * C;
}

// Slab multisplit: single u32 LDS atomic per edge (R12, measured-good).
__global__ __launch_bounds__(RB) void k_reorder(const int* __restrict__ src,
                                                const int* __restrict__ dst,
                                                unsigned* __restrict__ fill,
                                                unsigned* __restrict__ perm, int E) {
    __shared__ unsigned slab[MAXB * CAP];  // 57344 B
    __shared__ unsigned ptr[MAXB];
    __shared__ unsigned gbase[MAXB];
    int tid = threadIdx.x;
    if (tid < MAXB) ptr[tid] = 0u;
    __syncthreads();
    long base0 = (long)blockIdx.x * CHUNK;
    int total = (int)min((long)CHUNK, (long)E - base0);
    bool full = (total == CHUNK);

    if (full) {
        const iv4* dv4 = (const iv4*)(dst + base0);
        const iv4* sv4 = (const iv4*)(src + base0);
        #pragma unroll
        for (int k = 0; k < 2; k++) {
            iv4 dq = dv4[k * RB + tid];
            iv4 sq = sv4[k * RB + tid];
            unsigned d, b, val, lpos;
            d = (unsigned)dq.x; b = d >> W_SHIFT;
            val = (unsigned)sq.x | ((d & (W - 1)) << 20);
            lpos = atomicAdd(&ptr[b], 1u);
            if (lpos < (unsigned)CAP) slab[b * CAP + lpos] = val;
            else perm[atomicAdd(&fill[b], 1u)] = val;
            d = (unsigned)dq.y; b = d >> W_SHIFT;
            val = (unsigned)sq.y | ((d & (W - 1)) << 20);
            lpos = atomicAdd(&ptr[b], 1u);
            if (lpos < (unsigned)CAP) slab[b * CAP + lpos] = val;
            else perm[atomicAdd(&fill[b], 1u)] = val;
            d = (unsigned)dq.z; b = d >> W_SHIFT;
            val = (unsigned)sq.z | ((d & (W - 1)) << 20);
            lpos = atomicAdd(&ptr[b], 1u);
            if (lpos < (unsigned)CAP) slab[b * CAP + lpos] = val;
            else perm[atomicAdd(&fill[b], 1u)] = val;
            d = (unsigned)dq.w; b = d >> W_SHIFT;
            val = (unsigned)sq.w | ((d & (W - 1)) << 20);
            lpos = atomicAdd(&ptr[b], 1u);
            if (lpos < (unsigned)CAP) slab[b * CAP + lpos] = val;
            else perm[atomicAdd(&fill[b], 1u)] = val;
        }
    } else {
        for (int li = tid; li < total; li += RB) {
            unsigned d = (unsigned)dst[base0 + li];
            unsigned s = (unsigned)src[base0 + li];
            unsigned b = d >> W_SHIFT;
            unsigned val = s | ((d & (W - 1)) << 20);
            unsigned lpos = atomicAdd(&ptr[b], 1u);
            if (lpos < (unsigned)CAP) slab[b * CAP + lpos] = val;
            else perm[atomicAdd(&fill[b], 1u)] = val;
        }
    }
    __syncthreads();
    if (tid < MAXB) {
        unsigned cnt = min(ptr[tid], (unsigned)CAP);
        gbase[tid] = cnt ? atomicAdd(&fill[tid], cnt) : 0u;
        ptr[tid] = cnt;
    }
    __syncthreads();
    for (int s = tid; s < MAXB * CAP; s += RB) {
        int b = s / CAP;
        int i = s - b * CAP;
        if (i < (int)ptr[b]) perm[gbase[b] + i] = slab[s];
    }
}

// Count per-dst + scan -> offs/xs, then 4 place phases (512 dsts each):
// stream window edges, place quarter edges into LDS staging at exact
// positions, coalesced write-out to compact perm2. 2 u32 atomics/edge.
__global__ __launch_bounds__(AB) void k_sortwin2(const unsigned* __restrict__ perm,
                                                 const unsigned* __restrict__ fill,
                                                 const float2* __restrict__ x,
                                                 __half2* __restrict__ xs,
                                                 unsigned* __restrict__ offs,
                                                 unsigned* __restrict__ perm2,
                                                 int N, unsigned C, int NB,
                                                 unsigned Etot) {
    __shared__ unsigned shm[2 * W];   // counts (x2) -> abs write ptrs [0..W)
    __shared__ unsigned stg[STG];     // quarter staging (44KB)
    __shared__ unsigned scn[AB];
    __shared__ unsigned qb[5];
    const int tid = threadIdx.x;
    const int b = blockIdx.x;

    // compact window-base scan over per-window fills
    unsigned wsz = (tid < NB) ? (fill[tid] - (unsigned)tid * C) : 0u;
    scn[tid] = wsz;
    __syncthreads();
    for (int off = 1; off < AB; off <<= 1) {
        unsigned u = (tid >= off) ? scn[tid - off] : 0u;
        __syncthreads();
        scn[tid] += u;
        __syncthreads();
    }
    unsigned wb = (b > 0) ? scn[b - 1] : 0u;   // compact base of this window
    if (b == NB - 1 && tid == 0) offs[(unsigned)NB << W_SHIFT] = Etot;
    for (int i = tid; i < 2 * W; i += AB) shm[i] = 0u;
    __syncthreads();

    unsigned s = (unsigned)b * C, e = fill[b];
    unsigned m = e - s, nv8 = m >> 3;
    unsigned par = tid & 1u;
    const uv4* p4 = (const uv4*)(perm + s);

    // ---- count pass (x2-replicated) ----
    for (unsigned j = tid; j < nv8; j += AB) {
        uv4 qa = p4[2u * j];
        uv4 qv = p4[2u * j + 1u];
        atomicAdd(&shm[((qa.x >> 20) << 1) | par], 1u);
        atomicAdd(&shm[((qa.y >> 20) << 1) | par], 1u);
        atomicAdd(&shm[((qa.z >> 20) << 1) | par], 1u);
        atomicAdd(&shm[((qa.w >> 20) << 1) | par], 1u);
        atomicAdd(&shm[((qv.x >> 20) << 1) | par], 1u);
        atomicAdd(&shm[((qv.y >> 20) << 1) | par], 1u);
        atomicAdd(&shm[((qv.z >> 20) << 1) | par], 1u);
        atomicAdd(&shm[((qv.w >> 20) << 1) | par], 1u);
    }
    unsigned t8 = s + (nv8 << 3) + (unsigned)tid;
    if (t8 < e) atomicAdd(&shm[((perm[t8] >> 20) << 1) | par], 1u);
    __syncthreads();

    // ---- merge + block scan of 2048 counts -> absolute compact offsets ----
    int l0 = 4 * tid;
    unsigned c0 = shm[2 * l0]     + shm[2 * l0 + 1];
    unsigned c1 = shm[2 * l0 + 2] + shm[2 * l0 + 3];
    unsigned c2 = shm[2 * l0 + 4] + shm[2 * l0 + 5];
    unsigned c3 = shm[2 * l0 + 6] + shm[2 * l0 + 7];
    unsigned sum4 = c0 + c1 + c2 + c3;
    scn[tid] = sum4;
    __syncthreads();
    for (int off = 1; off < AB; off <<= 1) {
        unsigned u = (tid >= off) ? scn[tid - off] : 0u;
        __syncthreads();
        scn[tid] += u;
        __syncthreads();
    }
    unsigned o0 = wb + (scn[tid] - sum4);
    unsigned o1 = o0 + c0, o2 = o1 + c1, o3 = o2 + c2;
    shm[l0] = o0; shm[l0 + 1] = o1; shm[l0 + 2] = o2; shm[l0 + 3] = o3;
    if ((tid & 127) == 0) qb[tid >> 7] = o0;   // quarter compact bases
    if (tid == 0) qb[4] = wb + m;              // window compact end
    int d0 = (b << W_SHIFT) + l0;
    offs[d0] = o0; offs[d0 + 1] = o1; offs[d0 + 2] = o2; offs[d0 + 3] = o3;
    unsigned cc[4] = {c0, c1, c2, c3};
    #pragma unroll
    for (int k = 0; k < 4; k++) {
        int d = d0 + k;
        if (d < N) {
            float dv = 1.0f / sqrtf((float)cc[k] + 1.0f);   // +1 self-loop
            float2 xv = x[d];
            xs[d] = __floats2half2_rn(xv.x * dv, xv.y * dv);
        }
    }
    __syncthreads();

    // ---- 4 place phases: LDS-staged, coalesced write-out ----
    for (int q = 0; q < 4; q++) {
        unsigned qlo = qb[q], qhi = qb[q + 1];
        for (unsigned j = tid; j < nv8; j += AB) {
            uv4 qa = p4[2u * j];
            uv4 qv = p4[2u * j + 1u];
            unsigned vv[8] = {qa.x, qa.y, qa.z, qa.w, qv.x, qv.y, qv.z, qv.w};
            #pragma unroll
            for (int k = 0; k < 8; k++) {
                unsigned v = vv[k];
                unsigned dl = v >> 20;
                if ((dl >> 9) == (unsigned)q) {
                    unsigned pos = atomicAdd(&shm[dl], 1u);
                    unsigned loc = pos - qlo;
                    if (loc < (unsigned)STG) stg[loc] = v;
                    else perm2[pos] = v;    // overflow: rare, still correct
                }
            }
        }
        if (t8 < e) {
            unsigned v = perm[t8];
            unsigned dl = v >> 20;
            if ((dl >> 9) == (unsigned)q) {
                unsigned pos = atomicAdd(&shm[dl], 1u);
                unsigned loc = pos - qlo;
                if (loc < (unsigned)STG) stg[loc] = v;
                else perm2[pos] = v;
            }
        }
        __syncthreads();
        unsigned qn = qhi - qlo;
        unsigned nw = qn < (unsigned)STG ? qn : (unsigned)STG;
        for (unsigned i = tid; i < nw; i += AB)
            perm2[qlo + i] = stg[i];
        __syncthreads();
    }
}

// layer1: per quarter, stage gathered values in LDS (coalesced perm2 read,
// random xs gather, XOR-swizzled LDS write), then one thread per dst sums
// its segment from LDS + full MLP. No atomics.
__global__ __launch_bounds__(AB) void k_gacc1s(const unsigned* __restrict__ perm2,
                                               const unsigned* __restrict__ offs,
                                               const __half2* __restrict__ xs,
                                               const float* __restrict__ W1,
                                               const float* __restrict__ b1,
                                               const float* __restrict__ W2,
                                               __half2* __restrict__ h2s, int N) {
    __shared__ unsigned vstage[STG];
    const int tid = threadIdx.x;
    const int dbase = (int)blockIdx.x << W_SHIFT;
    const unsigned* xsu = (const unsigned*)xs;
    float w10 = W1[0], w11 = W1[1], w12 = W1[2], w13 = W1[3];
    float w14 = W1[4], w15 = W1[5], w16 = W1[6], w17 = W1[7];
    float bb0 = b1[0], bb1 = b1[1], bb2 = b1[2], bb3 = b1[3];
    float u0 = W2[0], u1 = W2[1], u2 = W2[2], u3 = W2[3];
    float u4 = W2[4], u5 = W2[5], u6 = W2[6], u7 = W2[7];
    for (int q = 0; q < 4; q++) {
        int dq = dbase + (q << 9);
        unsigned qlo = offs[dq];
        unsigned qhi = offs[dq + 512];
        unsigned qn = qhi - qlo;
        unsigned nst = qn < (unsigned)STG ? qn : (unsigned)STG;
        for (unsigned i = tid; i < nst; i += AB) {
            unsigned v = perm2[qlo + i];
            vstage[i ^ ((i >> 5) & 31u)] = xsu[v & 0xFFFFFu];
        }
        __syncthreads();
        int d = dq + tid;
        if (d < N) {
            unsigned st = offs[d], en = offs[d + 1];
            float dv = 1.0f / sqrtf((float)(en - st) + 1.0f);
            float2 self = __half22float2(xs[d]);
            float Sx = self.x, Sy = self.y;
            for (unsigned p = st; p < en; p++) {
                unsigned loc = p - qlo;
                unsigned uval;
                if (loc < (unsigned)STG) {
                    uval = vstage[loc ^ ((loc >> 5) & 31u)];
                } else {
                    unsigned v = perm2[p];
                    uval = xsu[v & 0xFFFFFu];
                }
                __half2 hv = *reinterpret_cast<__half2*>(&uval);
                float2 vf = __half22float2(hv);
                Sx += vf.x; Sy += vf.y;
            }
            float a0 = fmaxf(fmaf(Sy, w14, Sx * w10) * dv + bb0, 0.0f);
            float a1 = fmaxf(fmaf(Sy, w15, Sx * w11) * dv + bb1, 0.0f);
            float a2 = fmaxf(fmaf(Sy, w16, Sx * w12) * dv + bb2, 0.0f);
            float a3 = fmaxf(fmaf(Sy, w17, Sx * w13) * dv + bb3, 0.0f);
            float hx = (a0 * u0 + a1 * u2 + a2 * u4 + a3 * u6) * dv;
            float hy = (a0 * u1 + a1 * u3 + a2 * u5 + a3 * u7) * dv;
            h2s[d] = __floats2half2_rn(hx, hy);
        }
        __syncthreads();
    }
}

// layer2: same structure, gathers h2s, epilogue = *dv + bias.
__global__ __launch_bounds__(AB) void k_gacc2s(const unsigned* __restrict__ perm2,
                                               const unsigned* __restrict__ offs,
                                               const __half2* __restrict__ h2s,
                                               const float* __restrict__ b2,
                                               float2* __restrict__ out, int N) {
    __shared__ unsigned vstage[STG];
    const int tid = threadIdx.x;
    const int dbase = (int)blockIdx.x << W_SHIFT;
    const unsigned* hu = (const unsigned*)h2s;
    float bb0 = b2[0], bb1 = b2[1];
    for (int q = 0; q < 4; q++) {
        int dq = dbase + (q << 9);
        unsigned qlo = offs[dq];
        unsigned qhi = offs[dq + 512];
        unsigned qn = qhi - qlo;
        unsigned nst = qn < (unsigned)STG ? qn : (unsigned)STG;
        for (unsigned i = tid; i < nst; i += AB) {
            unsigned v = perm2[qlo + i];
            vstage[i ^ ((i >> 5) & 31u)] = hu[v & 0xFFFFFu];
        }
        __syncthreads();
        int d = dq + tid;
        if (d < N) {
            unsigned st = offs[d], en = offs[d + 1];
            float dv = 1.0f / sqrtf((float)(en - st) + 1.0f);
            float2 self = __half22float2(h2s[d]);
            float Sx = self.x, Sy = self.y;
            for (unsigned p = st; p < en; p++) {
                unsigned loc = p - qlo;
                unsigned uval;
                if (loc < (unsigned)STG) {
                    uval = vstage[loc ^ ((loc >> 5) & 31u)];
                } else {
                    unsigned v = perm2[p];
                    uval = hu[v & 0xFFFFFu];
                }
                __half2 hv = *reinterpret_cast<__half2*>(&uval);
                float2 vf = __half22float2(hv);
                Sx += vf.x; Sy += vf.y;
            }
            out[d] = make_float2(Sx * dv + bb0, Sy * dv + bb1);
        }
        __syncthreads();
    }
}

// ---------- R12 tier (fallback if sorted-path workspace too small) ----------

__global__ __launch_bounds__(AB) void k_dinv(const unsigned* __restrict__ perm,
                                             const unsigned* __restrict__ fill,
                                             const float2* __restrict__ x,
                                             float* __restrict__ dinv,
                                             unsigned* __restrict__ deg,
                                             __half2* __restrict__ xs,
                                             int N, unsigned C) {
    __shared__ unsigned c[2 * W];
    for (int i = threadIdx.x; i < 2 * W; i += AB) c[i] = 0u;
    __syncthreads();
    int b = blockIdx.x;
    unsigned par = threadIdx.x & 1u;
    unsigned s = (unsigned)b * C, e = fill[b];
    unsigned m = e - s, nv8 = m >> 3;
    const uv4* p4 = (const uv4*)(perm + s);
    for (unsigned j = threadIdx.x; j < nv8; j += AB) {
        uv4 qa = __builtin_nontemporal_load(p4 + 2u * j);
        uv4 qb = __builtin_nontemporal_load(p4 + 2u * j + 1u);
        atomicAdd(&c[((qa.x >> 20) << 1) | par], 1u);
        atomicAdd(&c[((qa.y >> 20) << 1) | par], 1u);
        atomicAdd(&c[((qa.z >> 20) << 1) | par], 1u);
        atomicAdd(&c[((qa.w >> 20) << 1) | par], 1u);
        atomicAdd(&c[((qb.x >> 20) << 1) | par], 1u);
        atomicAdd(&c[((qb.y >> 20) << 1) | par], 1u);
        atomicAdd(&c[((qb.z >> 20) << 1) | par], 1u);
        atomicAdd(&c[((qb.w >> 20) << 1) | par], 1u);
    }
    unsigned t = s + (nv8 << 3) + threadIdx.x;
    if (t < e) atomicAdd(&c[((perm[t] >> 20) << 1) | par], 1u);
    __syncthreads();
    int d0 = b << W_SHIFT;
    for (int l = threadIdx.x; l < W; l += AB) {
        int d = d0 + l;
        if (d < N) {
            unsigned cn = c[2 * l] + c[2 * l + 1];
            float dv = 1.0f / sqrtf((float)(cn + 1u));
            dinv[d] = dv;
            deg[d] = cn;
            float2 xv = x[d];
            xs[d] = __floats2half2_rn(xv.x * dv, xv.y * dv);
        }
    }
}

__global__ __launch_bounds__(AB) void k_acc1(const unsigned* __restrict__ perm,
                                             const unsigned* __restrict__ fill,
                                             const __half2* __restrict__ xs,
                                             const float* __restrict__ dinv,
                                             const unsigned* __restrict__ deg,
                                             const float* __restrict__ W1,
                                             const float* __restrict__ b1,
                                             const float* __restrict__ W2,
                                             __half2* __restrict__ h2s,
                                             int N, unsigned C) {
    __shared__ unsigned long long acc[2 * W];
    for (int i = threadIdx.x; i < 2 * W; i += AB) acc[i] = 0ull;
    __syncthreads();
    int b = blockIdx.x;
    unsigned par = threadIdx.x & 1u;
    unsigned s = (unsigned)b * C, e = fill[b];
    unsigned m = e - s, nv8 = m >> 3;
    const uv4* p4 = (const uv4*)(perm + s);
    for (unsigned j = threadIdx.x; j < nv8; j += AB) {
        uv4 qa = __builtin_nontemporal_load(p4 + 2u * j);
        uv4 qb = __builtin_nontemporal_load(p4 + 2u * j + 1u);
        float2 v0 = __half22float2(xs[qa.x & 0xFFFFFu]);
        float2 v1 = __half22float2(xs[qa.y & 0xFFFFFu]);
        float2 v2 = __half22float2(xs[qa.z & 0xFFFFFu]);
        float2 v3 = __half22float2(xs[qa.w & 0xFFFFFu]);
        float2 v4 = __half22float2(xs[qb.x & 0xFFFFFu]);
        float2 v5 = __half22float2(xs[qb.y & 0xFFFFFu]);
        float2 v6 = __half22float2(xs[qb.z & 0xFFFFFu]);
        float2 v7 = __half22float2(xs[qb.w & 0xFFFFFu]);
        atomicAdd(&acc[((qa.x >> 20) << 1) | par], pack2(v0.x, v0.y, SCALE1, BIAS1));
        atomicAdd(&acc[((qa.y >> 20) << 1) | par], pack2(v1.x, v1.y, SCALE1, BIAS1));
        atomicAdd(&acc[((qa.z >> 20) << 1) | par], pack2(v2.x, v2.y, SCALE1, BIAS1));
        atomicAdd(&acc[((qa.w >> 20) << 1) | par], pack2(v3.x, v3.y, SCALE1, BIAS1));
        atomicAdd(&acc[((qb.x >> 20) << 1) | par], pack2(v4.x, v4.y, SCALE1, BIAS1));
        atomicAdd(&acc[((qb.y >> 20) << 1) | par], pack2(v5.x, v5.y, SCALE1, BIAS1));
        atomicAdd(&acc[((qb.z >> 20) << 1) | par], pack2(v6.x, v6.y, SCALE1, BIAS1));
        atomicAdd(&acc[((qb.w >> 20) << 1) | par], pack2(v7.x, v7.y, SCALE1, BIAS1));
    }
    unsigned t = s + (nv8 << 3) + threadIdx.x;
    if (t < e) {
        unsigned p = perm[t];
        float2 v = __half22float2(xs[p & 0xFFFFFu]);
        atomicAdd(&acc[((p >> 20) << 1) | par], pack2(v.x, v.y, SCALE1, BIAS1));
    }
    __syncthreads();
    int d0 = b << W_SHIFT;
    float w10 = W1[0], w11 = W1[1], w12 = W1[2], w13 = W1[3];
    float w14 = W1[4], w15 = W1[5], w16 = W1[6], w17 = W1[7];
    float bb0 = b1[0], bb1 = b1[1], bb2 = b1[2], bb3 = b1[3];
    float u0 = W2[0], u1 = W2[1], u2 = W2[2], u3 = W2[3];
    float u4 = W2[4], u5 = W2[5], u6 = W2[6], u7 = W2[7];
    for (int l = threadIdx.x; l < W; l += AB) {
        int d = d0 + l;
        if (d < N) {
            float dv = dinv[d];
            unsigned cn = deg[d];
            unsigned long long a64 = acc[2 * l] + acc[2 * l + 1];
            unsigned lo = (unsigned)a64, hi = (unsigned)(a64 >> 32);
            float2 self = __half22float2(xs[d]);
            float Sx = (float)(int)(lo - cn * BIAS1) * INV1 + self.x;
            float Sy = (float)(int)(hi - cn * BIAS1) * INV1 + self.y;
            float a0 = fmaxf(fmaf(Sy, w14, Sx * w10) * dv + bb0, 0.0f);
            float a1 = fmaxf(fmaf(Sy, w15, Sx * w11) * dv + bb1, 0.0f);
            float a2 = fmaxf(fmaf(Sy, w16, Sx * w12) * dv + bb2, 0.0f);
            float a3 = fmaxf(fmaf(Sy, w17, Sx * w13) * dv + bb3, 0.0f);
            float hx = (a0 * u0 + a1 * u2 + a2 * u4 + a3 * u6) * dv;
            float hy = (a0 * u1 + a1 * u3 + a2 * u5 + a3 * u7) * dv;
            h2s[d] = __floats2half2_rn(hx, hy);
        }
    }
}

__global__ __launch_bounds__(AB) void k_acc2(const unsigned* __restrict__ perm,
                                             const unsigned* __restrict__ fill,
                                             const __half2* __restrict__ h2s,
                                             const float* __restrict__ dinv,
                                             const unsigned* __restrict__ deg,
                                             const float* __restrict__ b2,
                                             float2* __restrict__ out,
                                             int N, unsigned C) {
    __shared__ unsigned long long acc[2 * W];
    for (int i = threadIdx.x; i < 2 * W; i += AB) acc[i] = 0ull;
    __syncthreads();
    int b = blockIdx.x;
    unsigned par = threadIdx.x & 1u;
    unsigned s = (unsigned)b * C, e = fill[b];
    unsigned m = e - s, nv8 = m >> 3;
    const uv4* p4 = (const uv4*)(perm + s);
    for (unsigned j = threadIdx.x; j < nv8; j += AB) {
        uv4 qa = __builtin_nontemporal_load(p4 + 2u * j);
        uv4 qb = __builtin_nontemporal_load(p4 + 2u * j + 1u);
        float2 v0 = __half22float2(h2s[qa.x & 0xFFFFFu]);
        float2 v1 = __half22float2(h2s[qa.y & 0xFFFFFu]);
        float2 v2 = __half22float2(h2s[qa.z & 0xFFFFFu]);
        float2 v3 = __half22float2(h2s[qa.w & 0xFFFFFu]);
        float2 v4 = __half22float2(h2s[qb.x & 0xFFFFFu]);
        float2 v5 = __half22float2(h2s[qb.y & 0xFFFFFu]);
        float2 v6 = __half22float2(h2s[qb.z & 0xFFFFFu]);
        float2 v7 = __half22float2(h2s[qb.w & 0xFFFFFu]);
        atomicAdd(&acc[((qa.x >> 20) << 1) | par], pack2(v0.x, v0.y, SCALE2, BIAS2));
        atomicAdd(&acc[((qa.y >> 20) << 1) | par], pack2(v1.x, v1.y, SCALE2, BIAS2));
        atomicAdd(&acc[((qa.z >> 20) << 1) | par], pack2(v2.x, v2.y, SCALE2, BIAS2));
        atomicAdd(&acc[((qa.w >> 20) << 1) | par], pack2(v3.x, v3.y, SCALE2, BIAS2));
        atomicAdd(&acc[((qb.x >> 20) << 1) | par], pack2(v4.x, v4.y, SCALE2, BIAS2));
        atomicAdd(&acc[((qb.y >> 20) << 1) | par], pack2(v5.x, v5.y, SCALE2, BIAS2));
        atomicAdd(&acc[((qb.z >> 20) << 1) | par], pack2(v6.x, v6.y, SCALE2, BIAS2));
        atomicAdd(&acc[((qb.w >> 20) << 1) | par], pack2(v7.x, v7.y, SCALE2, BIAS2));
    }
    unsigned t = s + (nv8 << 3) + threadIdx.x;
    if (t < e) {
        unsigned p = perm[t];
        float2 v = __half22float2(h2s[p & 0xFFFFFu]);
        atomicAdd(&acc[((p >> 20) << 1) | par], pack2(v.x, v.y, SCALE2, BIAS2));
    }
    __syncthreads();
    int d0 = b << W_SHIFT;
    float bb0 = b2[0], bb1 = b2[1];
    for (int l = threadIdx.x; l < W; l += AB) {
        int d = d0 + l;
        if (d < N) {
            float dv = dinv[d];
            unsigned cn = deg[d];
            unsigned long long a64 = acc[2 * l] + acc[2 * l + 1];
            unsigned lo = (unsigned)a64, hi = (unsigned)(a64 >> 32);
            float2 v = __half22float2(h2s[d]);
            float Sx = (float)(int)(lo - cn * BIAS2) * INV2 + v.x;
            float Sy = (float)(int)(hi - cn * BIAS2) * INV2 + v.y;
            out[d] = make_float2(Sx * dv + bb0, Sy * dv + bb1);
        }
    }
}

// ---------------- fallback (R1-style, only if workspace too small) ----------

__global__ __launch_bounds__(256) void f_init_deg(unsigned* deg, int n) {
    int i = blockIdx.x * 256 + threadIdx.x;
    if (i < n) deg[i] = 1u;
}
__global__ __launch_bounds__(256) void f_count_deg(const int* dst, unsigned* deg, int E) {
    int e = blockIdx.x * 256 + threadIdx.x;
    if (e < E) atomicAdd(&deg[dst[e]], 1u);
}
__global__ __launch_bounds__(256) void f_node1(const float2* x, const float* W1,
                                               const unsigned* deg, float* dinv,
                                               float4* h1s, float4* agg1, int n) {
    int i = blockIdx.x * 256 + threadIdx.x;
    if (i >= n) return;
    float dv = 1.0f / sqrtf((float)deg[i]);
    dinv[i] = dv;
    float2 xv = x[i];
    float4 h;
    h.x = fmaf(xv.y, W1[4], xv.x * W1[0]) * dv;
    h.y = fmaf(xv.y, W1[5], xv.x * W1[1]) * dv;
    h.z = fmaf(xv.y, W1[6], xv.x * W1[2]) * dv;
    h.w = fmaf(xv.y, W1[7], xv.x * W1[3]) * dv;
    h1s[i] = h;
    agg1[i] = make_float4(h.x * dv, h.y * dv, h.z * dv, h.w * dv);
}
__global__ __launch_bounds__(256) void f_edge1(const int* src, const int* dst,
                                               const float* dinv, const float4* h1s,
                                               float* agg1, int E) {
    int e = blockIdx.x * 256 + threadIdx.x;
    if (e >= E) return;
    int s = src[e], d = dst[e];
    float w = dinv[d];
    float4 m = h1s[s];
    float* p = agg1 + 4ll * d;
    unsafeAtomicAdd(p + 0, m.x * w);
    unsafeAtomicAdd(p + 1, m.y * w);
    unsafeAtomicAdd(p + 2, m.z * w);
    unsafeAtomicAdd(p + 3, m.w * w);
}
__global__ __launch_bounds__(256) void f_node2(const float4* agg1, const float* b1,
                                               const float* W2, const float* b2,
                                               const float* dinv, float2* h2s,
                                               float2* out, int n) {
    int i = blockIdx.x * 256 + threadIdx.x;
    if (i >= n) return;
    float4 a = agg1[i];
    a.x = fmaxf(a.x + b1[0], 0.0f);
    a.y = fmaxf(a.y + b1[1], 0.0f);
    a.z = fmaxf(a.z + b1[2], 0.0f);
    a.w = fmaxf(a.w + b1[3], 0.0f);
    float dv = dinv[i];
    float2 h;
    h.x = (a.x * W2[0] + a.y * W2[2] + a.z * W2[4] + a.w * W2[6]) * dv;
    h.y = (a.x * W2[1] + a.y * W2[3] + a.z * W2[5] + a.w * W2[7]) * dv;
    h2s[i] = h;
    out[i] = make_float2(b2[0] + h.x * dv, b2[1] + h.y * dv);
}
__global__ __launch_bounds__(256) void f_edge2(const int* src, const int* dst,
                                               const float* dinv, const float2* h2s,
                                               float* out, int E) {
    int e = blockIdx.x * 256 + threadIdx.x;
    if (e >= E) return;
    int s = src[e], d = dst[e];
    float w = dinv[d];
    float2 m = h2s[s];
    float* p = out + 2ll * d;
    unsafeAtomicAdd(p + 0, m.x * w);
    unsafeAtomicAdd(p + 1, m.y * w);
}

extern "C" void kernel_launch(void* const* d_in, const int* in_sizes, int n_in,
                              void* d_out, int out_size, void* d_ws, size_t ws_size,
                              hipStream_t stream) {
    const float* x  = (const float*)d_in[0];
    const int* ei   = (const int*)d_in[1];
    const float* W1 = (const float*)d_in[2];
    const float* b1 = (const float*)d_in[3];
    const float* W2 = (const float*)d_in[4];
    const float* b2 = (const float*)d_in[5];
    float* out = (float*)d_out;

    const int N = in_sizes[0] / 2;
    const int E = in_sizes[1] / 2;
    const int* src = ei;
    const int* dst = ei + E;
    const int NB = (N + W - 1) >> W_SHIFT;

    char* ws = (char*)d_ws;
    const int gN = (N + 255) / 256;
    const int gE = (E + 255) / 256;

    const long Cmin = (long)(E / (NB > 0 ? NB : 1)) + 4096;
    auto rnd = [](size_t v) { return (v + 63) & ~(size_t)63; };

    // ---- tier 1: fully dst-sorted path ----
    size_t sz_xs   = rnd((size_t)4 * N);
    size_t sz_h2s  = rnd((size_t)4 * N);
    size_t sz_offs = rnd((size_t)4 * ((size_t)NB * W + 64));
    size_t sz_p2   = rnd((size_t)4 * (size_t)E);
    size_t fixed3  = 32768 + sz_xs + sz_h2s + sz_offs + sz_p2;
    long avail3 = (long)ws_size - (long)fixed3;
    long Cmax3 = (avail3 > 0) ? avail3 / (4L * NB) : 0;
    long Cw3 = (Cmax3 > Cmin + 8192) ? (Cmin + 8192) : Cmax3;
    unsigned C3 = (unsigned)(Cw3 & ~7L);
    bool fast3 = ((long)C3 >= Cmin) && (NB <= MAXB) && (N <= (1 << 20)) && (E > 0);

    // ---- tier 2: R12 LDS-atomic path ----
    size_t fixed = 32768 + (size_t)16 * N;
    long avail = (long)ws_size - (long)fixed;
    long Cmax = (avail > 0) ? avail / (4L * NB) : 0;
    long Cw = (Cmax > Cmin + 8192) ? (Cmin + 8192) : Cmax;
    unsigned C = (unsigned)(Cw & ~7L);
    bool fast = ((long)C >= Cmin) && (NB <= MAXB) && (N <= (1 << 20));

    if (fast3) {
        unsigned* fill  = (unsigned*)ws;
        __half2*  xs    = (__half2*)(ws + 32768);
        __half2*  h2s   = (__half2*)(ws + 32768 + sz_xs);
        unsigned* offs  = (unsigned*)(ws + 32768 + sz_xs + sz_h2s);
        unsigned* perm2 = (unsigned*)(ws + 32768 + sz_xs + sz_h2s + sz_offs);
        unsigned* perm  = (unsigned*)(ws + fixed3);

        k_zero_fill<<<(NB + 255) / 256, 256, 0, stream>>>(fill, NB, C3);
        k_reorder<<<(E + CHUNK - 1) / CHUNK, RB, 0, stream>>>(src, dst, fill, perm, E);
        k_sortwin2<<<NB, AB, 0, stream>>>(perm, fill, (const float2*)x, xs, offs,
                                          perm2, N, C3, NB, (unsigned)E);
        k_gacc1s<<<NB, AB, 0, stream>>>(perm2, offs, xs, W1, b1, W2, h2s, N);
        k_gacc2s<<<NB, AB, 0, stream>>>(perm2, offs, h2s, b2, (float2*)out, N);
    } else if (fast) {
        unsigned* fill = (unsigned*)(ws);
        float*    dinv = (float*)(ws + 32768);
        unsigned* deg  = (unsigned*)(ws + 32768 + (size_t)4 * N);
        __half2*  xs   = (__half2*)(ws + 32768 + (size_t)8 * N);
        __half2*  h2s  = (__half2*)(ws + 32768 + (size_t)12 * N);
        unsigned* perm = (unsigned*)(ws + fixed);

        k_zero_fill<<<(NB + 255) / 256, 256, 0, stream>>>(fill, NB, C);
        k_reorder<<<(E + CHUNK - 1) / CHUNK, RB, 0, stream>>>(src, dst, fill, perm, E);
        k_dinv<<<NB, AB, 0, stream>>>(perm, fill, (const float2*)x, dinv, deg, xs, N, C);
        k_acc1<<<NB, AB, 0, stream>>>(perm, fill, xs, dinv, deg, W1, b1, W2, h2s, N, C);
        k_acc2<<<NB, AB, 0, stream>>>(perm, fill, h2s, dinv, deg, b2, (float2*)out, N, C);
    } else {
        unsigned* deg = (unsigned*)(ws);
        float* dinv   = (float*)(ws + (size_t)4 * N);
        float* h1s    = (float*)(ws + (size_t)8 * N);
        float* agg1   = (float*)(ws + (size_t)24 * N);
        float* h2s    = h1s;

        f_init_deg<<<gN, 256, 0, stream>>>(deg, N);
        f_count_deg<<<gE, 256, 0, stream>>>(dst, deg, E);
        f_node1<<<gN, 256, 0, stream>>>((const float2*)x, W1, deg, dinv,
                                        (float4*)h1s, (float4*)agg1, N);
        f_edge1<<<gE, 256, 0, stream>>>(src, dst, dinv, (const float4*)h1s, agg1, E);
        f_node2<<<gN, 256, 0, stream>>>((const float4*)agg1, b1, W2, b2, dinv,
                                        (float2*)h2s, (float2*)out, N);
        f_edge2<<<gE, 256, 0, stream>>>(src, dst, dinv, (const float2*)h2s, out, E);
    }
}